// Round 4
// baseline (1852.513 us; speedup 1.0000x reference)
//
#include <hip/hip_runtime.h>

// Locally connected layer:
// out[b,o,h,w] = sum_{c,i,j} x[b,c,h+i,w+j] * W[o,c,h,w,i,j] + bias[o,h,w]
// x: [32,32,64,64] f32, W: [64,32,62,62,3,3] f32, bias: [64,62,62] f32
// out: [32,64,62,62] f32
//
// Latency-bound analysis (R3): x loads must be L2 hits and pipelined.
// - XCD swizzle: block i lands on XCD i%8 (round-robin). Remap so each XCD
//   owns a contiguous 124-block chunk (~8 h values) -> per-XCD x working set
//   ~2.9 MB fits the 4 MB L2.
// - xr double-buffer: issue batch bi+1's x loads before bi's FMAs so the
//   vmcnt wait is covered by 36 FMAs x 4 waves.
// - W has zero reuse: nontemporal loads keep the 283 MB stream from
//   evicting x out of L2/L3.

#define C_  32
#define B_  32
#define O_  64
#define H_  64
#define W_  64
#define OH_ 62
#define OW_ 62

typedef float vfloat2 __attribute__((ext_vector_type(2)));

__global__ __launch_bounds__(256, 4)
void lcl_kernel(const float* __restrict__ x,
                const float* __restrict__ Wt,
                const float* __restrict__ bias,
                float* __restrict__ out) {
    // ---- XCD-aware remap: launched id i -> XCD i%8. Give XCD k logical
    // blocks [k*124, (k+1)*124) so its x slab (h-chunk) fits L2.
    const int nblk    = (O_ / 4) * OH_;              // 992 = 8 * 124
    const int i       = blockIdx.x;
    const int logical = (i & 7) * (nblk >> 3) + (i >> 3);
    const int og      = logical & 15;                // o-group (fast) 0..15
    const int h       = logical >> 4;                // 0..61

    const int wave = threadIdx.x >> 6;               // 0..3
    const int o    = (og << 2) + wave;               // 0..63
    const int lane = threadIdx.x & 63;
    const int wg   = lane & 15;                      // w0 = 4*wg
    const int bg   = lane >> 4;                      // b0 = 8*bg
    const int w0   = wg * 4;
    const int b0   = bg * 8;
    const bool full = (wg < 15);                     // wg==15 covers only w=60,61

    float acc[8][4];
#pragma unroll
    for (int bi = 0; bi < 8; ++bi)
#pragma unroll
        for (int wi = 0; wi < 4; ++wi) acc[bi][wi] = 0.f;

    // W flat idx = o*(C*OH*OW*9) + c*(OH*OW*9) + h*(OW*9) + w*9 + i*3 + j
    const long wcstride = (long)OH_ * OW_ * 9;       // 34596
    const long wbase0   = (long)o * C_ * wcstride + (long)h * (OW_ * 9) + (long)w0 * 9;
    // x flat idx = ((b*C + c)*H + (h+i))*W + col
    const long xbstride = (long)C_ * H_ * W_;        // 131072
    const long xcstride = (long)H_ * W_;             // 4096
    const long xbase0   = (long)b0 * xbstride + (long)h * W_ + w0;

#define LOADX(dst, bidx) do {                                                  \
        const float* xb_ = xp + (long)(bidx) * xbstride;                       \
        _Pragma("unroll")                                                      \
        for (int i_ = 0; i_ < 3; ++i_) {                                       \
            const float* row_ = xb_ + i_ * W_;                                 \
            float4 v4_ = *reinterpret_cast<const float4*>(row_);               \
            dst[i_][0] = v4_.x; dst[i_][1] = v4_.y;                            \
            dst[i_][2] = v4_.z; dst[i_][3] = v4_.w;                            \
            if (full) {                                                        \
                float2 v2_ = *reinterpret_cast<const float2*>(row_ + 4);       \
                dst[i_][4] = v2_.x; dst[i_][5] = v2_.y;                        \
            } else { dst[i_][4] = 0.f; dst[i_][5] = 0.f; }                     \
        }                                                                      \
    } while (0)

    for (int c = 0; c < C_; ++c) {
        // ---- W: 36 floats (4 w positions x 9 taps), contiguous, 8B-aligned.
        // Nontemporal: W is single-use, don't evict x from the caches.
        const float* wp = Wt + wbase0 + (long)c * wcstride;
        float wv[36];
#pragma unroll
        for (int q = 0; q < 18; ++q) {
            if (q < 9 || full) {
                vfloat2 v = __builtin_nontemporal_load(
                    reinterpret_cast<const vfloat2*>(wp) + q);
                wv[2 * q] = v.x; wv[2 * q + 1] = v.y;
            } else {
                wv[2 * q] = 0.f; wv[2 * q + 1] = 0.f;
            }
        }

        const float* xp = x + xbase0 + (long)c * xcstride;

        // ---- software-pipelined batch loop: load bi+1 while FMA-ing bi
        float xr[2][3][6];
        LOADX(xr[0], 0);
#pragma unroll
        for (int bi = 0; bi < 8; ++bi) {
            if (bi < 7) LOADX(xr[(bi + 1) & 1], bi + 1);
            const float (*xc)[6] = xr[bi & 1];
#pragma unroll
            for (int wi = 0; wi < 4; ++wi)
#pragma unroll
                for (int ii = 0; ii < 3; ++ii)
#pragma unroll
                    for (int j = 0; j < 3; ++j)
                        acc[bi][wi] = fmaf(xc[ii][wi + j], wv[wi * 9 + ii * 3 + j],
                                           acc[bi][wi]);
        }
    }
#undef LOADX

    // ---- epilogue: bias + nontemporal float2 stores (8B-aligned: row stride
    // 248 B, offset w0*4 B).
    const float* brow = bias + ((long)o * OH_ + h) * OW_ + w0;
    float2 bv0 = *reinterpret_cast<const float2*>(brow);
    float2 bv1;
    if (full) bv1 = *reinterpret_cast<const float2*>(brow + 2);
    else { bv1.x = 0.f; bv1.y = 0.f; }

#pragma unroll
    for (int bi = 0; bi < 8; ++bi) {
        float* orow = out + (((long)(b0 + bi) * O_ + o) * OH_ + h) * OW_ + w0;
        vfloat2 s0; s0.x = acc[bi][0] + bv0.x; s0.y = acc[bi][1] + bv0.y;
        __builtin_nontemporal_store(s0, reinterpret_cast<vfloat2*>(orow));
        if (full) {
            vfloat2 s1; s1.x = acc[bi][2] + bv1.x; s1.y = acc[bi][3] + bv1.y;
            __builtin_nontemporal_store(s1, reinterpret_cast<vfloat2*>(orow) + 1);
        }
    }
}

extern "C" void kernel_launch(void* const* d_in, const int* in_sizes, int n_in,
                              void* d_out, int out_size, void* d_ws, size_t ws_size,
                              hipStream_t stream) {
    const float* x    = (const float*)d_in[0];
    const float* Wt   = (const float*)d_in[1];
    const float* bias = (const float*)d_in[2];
    float* out        = (float*)d_out;

    dim3 grid((O_ / 4) * OH_);   // 992 linear blocks, XCD-swizzled in-kernel
    dim3 block(256);
    lcl_kernel<<<grid, block, 0, stream>>>(x, Wt, bias, out);
}

// Round 5
// 472.907 us; speedup vs baseline: 3.9173x; 3.9173x over previous
//
#include <hip/hip_runtime.h>

// Locally connected layer:
// out[b,o,h,w] = sum_{c,i,j} x[b,c,h+i,w+j] * W[o,c,h,w,i,j] + bias[o,h,w]
// x: [32,32,64,64] f32, W: [64,32,62,62,3,3] f32, bias: [64,62,62] f32
// out: [32,64,62,62] f32
//
// R5: R4's ideas without the spill disaster.
// - Chunked XCD swizzle: block i -> XCD i%8; each XCD owns 124 contiguous
//   logical blocks (~8 h values) -> per-XCD x slab ~2.6 MB fits 4 MB L2.
// - Nontemporal W loads (283 MB single-use stream; don't evict x from L2).
// - xr double-buffer: issue batch bi+1's x loads before bi's 144 FMAs.
// - NO min-waves launch_bounds clause: R4's (256,4) forced VGPR=64 and
//   spilled 6 GB of scratch to HBM. Let allocator use ~130-160 VGPR.

#define C_  32
#define B_  32
#define O_  64
#define H_  64
#define W_  64
#define OH_ 62
#define OW_ 62

typedef float vfloat2 __attribute__((ext_vector_type(2)));

__global__ __launch_bounds__(256)
void lcl_kernel(const float* __restrict__ x,
                const float* __restrict__ Wt,
                const float* __restrict__ bias,
                float* __restrict__ out) {
    // ---- XCD-aware remap (hw: XCD = blockIdx.x % 8, round-robin)
    const int nblk    = (O_ / 4) * OH_;              // 992 = 8 * 124
    const int i       = blockIdx.x;
    const int logical = (i & 7) * (nblk >> 3) + (i >> 3);
    const int og      = logical & 15;                // o-group (fast) 0..15
    const int h       = logical >> 4;                // 0..61

    const int wave = threadIdx.x >> 6;               // 0..3
    const int o    = (og << 2) + wave;               // 0..63
    const int lane = threadIdx.x & 63;
    const int wg   = lane & 15;                      // w0 = 4*wg
    const int bg   = lane >> 4;                      // b0 = 8*bg
    const int w0   = wg * 4;
    const int b0   = bg * 8;
    const bool full = (wg < 15);                     // wg==15 covers only w=60,61

    float acc[8][4];
#pragma unroll
    for (int bi = 0; bi < 8; ++bi)
#pragma unroll
        for (int wi = 0; wi < 4; ++wi) acc[bi][wi] = 0.f;

    // W flat idx = o*(C*OH*OW*9) + c*(OH*OW*9) + h*(OW*9) + w*9 + i*3 + j
    const long wcstride = (long)OH_ * OW_ * 9;       // 34596
    const long wbase0   = (long)o * C_ * wcstride + (long)h * (OW_ * 9) + (long)w0 * 9;
    // x flat idx = ((b*C + c)*H + (h+i))*W + col
    const long xbstride = (long)C_ * H_ * W_;        // 131072
    const long xcstride = (long)H_ * W_;             // 4096
    const long xbase0   = (long)b0 * xbstride + (long)h * W_ + w0;

#define LOADX(dst, bidx) do {                                                  \
        const float* xb_ = xp + (long)(bidx) * xbstride;                       \
        _Pragma("unroll")                                                      \
        for (int i_ = 0; i_ < 3; ++i_) {                                       \
            const float* row_ = xb_ + i_ * W_;                                 \
            float4 v4_ = *reinterpret_cast<const float4*>(row_);               \
            dst[i_][0] = v4_.x; dst[i_][1] = v4_.y;                            \
            dst[i_][2] = v4_.z; dst[i_][3] = v4_.w;                            \
            if (full) {                                                        \
                float2 v2_ = *reinterpret_cast<const float2*>(row_ + 4);       \
                dst[i_][4] = v2_.x; dst[i_][5] = v2_.y;                        \
            } else { dst[i_][4] = 0.f; dst[i_][5] = 0.f; }                     \
        }                                                                      \
    } while (0)

    for (int c = 0; c < C_; ++c) {
        // ---- W: 36 floats (4 w x 9 taps), contiguous, 8B-aligned (h*2232B
        // can be odd multiples of 8 -> 16B NOT guaranteed, so float2 not
        // float4). Nontemporal: single-use stream.
        const float* wp = Wt + wbase0 + (long)c * wcstride;
        float wv[36];
#pragma unroll
        for (int q = 0; q < 18; ++q) {
            if (q < 9 || full) {
                vfloat2 v = __builtin_nontemporal_load(
                    reinterpret_cast<const vfloat2*>(wp) + q);
                wv[2 * q] = v.x; wv[2 * q + 1] = v.y;
            } else {
                wv[2 * q] = 0.f; wv[2 * q + 1] = 0.f;
            }
        }

        const float* xp = x + xbase0 + (long)c * xcstride;

        // ---- software-pipelined batch loop: load bi+1 while FMA-ing bi
        float xr[2][3][6];
        LOADX(xr[0], 0);
#pragma unroll
        for (int bi = 0; bi < 8; ++bi) {
            if (bi < 7) LOADX(xr[(bi + 1) & 1], bi + 1);
            const float (*xc)[6] = xr[bi & 1];
#pragma unroll
            for (int wi = 0; wi < 4; ++wi)
#pragma unroll
                for (int ii = 0; ii < 3; ++ii)
#pragma unroll
                    for (int j = 0; j < 3; ++j)
                        acc[bi][wi] = fmaf(xc[ii][wi + j], wv[wi * 9 + ii * 3 + j],
                                           acc[bi][wi]);
        }
    }
#undef LOADX

    // ---- epilogue: bias + nontemporal float2 stores (8B-aligned)
    const float* brow = bias + ((long)o * OH_ + h) * OW_ + w0;
    float2 bv0 = *reinterpret_cast<const float2*>(brow);
    float2 bv1;
    if (full) bv1 = *reinterpret_cast<const float2*>(brow + 2);
    else { bv1.x = 0.f; bv1.y = 0.f; }

#pragma unroll
    for (int bi = 0; bi < 8; ++bi) {
        float* orow = out + (((long)(b0 + bi) * O_ + o) * OH_ + h) * OW_ + w0;
        vfloat2 s0; s0.x = acc[bi][0] + bv0.x; s0.y = acc[bi][1] + bv0.y;
        __builtin_nontemporal_store(s0, reinterpret_cast<vfloat2*>(orow));
        if (full) {
            vfloat2 s1; s1.x = acc[bi][2] + bv1.x; s1.y = acc[bi][3] + bv1.y;
            __builtin_nontemporal_store(s1, reinterpret_cast<vfloat2*>(orow) + 1);
        }
    }
}

extern "C" void kernel_launch(void* const* d_in, const int* in_sizes, int n_in,
                              void* d_out, int out_size, void* d_ws, size_t ws_size,
                              hipStream_t stream) {
    const float* x    = (const float*)d_in[0];
    const float* Wt   = (const float*)d_in[1];
    const float* bias = (const float*)d_in[2];
    float* out        = (float*)d_out;

    dim3 grid((O_ / 4) * OH_);   // 992 linear blocks, XCD-swizzled in-kernel
    dim3 block(256);
    lcl_kernel<<<grid, block, 0, stream>>>(x, Wt, bias, out);
}

// Round 6
// 330.879 us; speedup vs baseline: 5.5988x; 1.4292x over previous
//
#include <hip/hip_runtime.h>

// Locally connected layer:
// out[b,o,h,w] = sum_{c,i,j} x[b,c,h+i,w+j] * W[o,c,h,w,i,j] + bias[o,h,w]
// x: [32,32,64,64] f32, W: [64,32,62,62,3,3] f32, bias: [64,62,62] f32
// out: [32,64,62,62] f32
//
// R6: LDS-staged x with async global_load_lds + double-buffer.
//  - Per block (4 waves = 4 o's, one h): x slab [32 batch][3 rows][64 cols]
//    = 24 KB per channel, staged ONCE per block per c (was 4x redundant
//    through a thrashing L1). Staging is issued DURING compute of the
//    previous channel; the __syncthreads vmcnt-drain lands after 288 FMAs.
//  - W: per-lane 18 float2 (REGULAR loads - R5 proved nontemporal kills the
//    8x intra-wave line reuse), double-buffered in registers (wvA/wvB,
//    static names), prefetched during compute.
//  - Chunked XCD swizzle kept: per-XCD x working set ~2.6 MB fits 4 MB L2.

#define C_  32
#define B_  32
#define O_  64
#define H_  64
#define W_  64
#define OH_ 62
#define OW_ 62

typedef float vfloat2 __attribute__((ext_vector_type(2)));

#define GLL16(gaddr, laddr)                                                     \
    __builtin_amdgcn_global_load_lds(                                           \
        (const __attribute__((address_space(1))) void*)(gaddr),                 \
        (__attribute__((address_space(3))) void*)(laddr), 16, 0, 0)

__global__ __launch_bounds__(256)
void lcl_kernel(const float* __restrict__ x,
                const float* __restrict__ Wt,
                const float* __restrict__ bias,
                float* __restrict__ out) {
    // x slab per channel: [batch][row][col] = [32][3][64] f32 = 24 KB, linear
    // (global_load_lds requires linear dest). +16 floats guard per buffer so
    // the masked-out tail b64 read of (batch31,row2,wg15) stays in-bounds.
    __shared__ float lds[2][6160];

    // ---- chunked XCD swizzle (hw: XCD = blockIdx.x % 8)
    const int nblk    = (O_ / 4) * OH_;              // 992 = 8 * 124
    const int i0      = blockIdx.x;
    const int logical = (i0 & 7) * (nblk >> 3) + (i0 >> 3);
    const int og      = logical & 15;                // o-group (fast)
    const int h       = logical >> 4;                // 0..61

    const int wv_i = threadIdx.x >> 6;               // wave 0..3
    const int o    = (og << 2) + wv_i;
    const int lane = threadIdx.x & 63;
    const int wg   = lane & 15;                      // w0 = 4*wg
    const int bg   = lane >> 4;                      // b0 = 8*bg
    const int w0   = wg * 4;
    const int b0   = bg * 8;
    const bool full = (wg < 15);

    // ---- per-lane global source offsets for the 6 gll instrs (const over c)
    // slab byte off S -> batch = S/768, within = S%768;
    // global byte off = batch*524288 + c*16384 + h*256 + within
    unsigned goff[6];
#pragma unroll
    for (int k = 0; k < 6; ++k) {
        unsigned S      = (unsigned)wv_i * 6144u + (unsigned)k * 1024u + (unsigned)lane * 16u;
        unsigned batch  = ((S >> 8) * 171u) >> 9;    // /768 for S<24576
        unsigned within = S - batch * 768u;
        goff[k] = batch * 524288u + (unsigned)h * 256u + within;
    }

    float acc[8][4];
#pragma unroll
    for (int bi = 0; bi < 8; ++bi)
#pragma unroll
        for (int wi = 0; wi < 4; ++wi) acc[bi][wi] = 0.f;

    // W flat idx = o*(C*OH*OW*9) + c*(OH*OW*9) + h*(OW*9) + w*9 + i*3 + j
    const long wcstride = (long)OH_ * OW_ * 9;       // 34596
    const long wbase0   = (long)o * C_ * wcstride + (long)h * (OW_ * 9) + (long)w0 * 9;

#define STAGE(bufptr, cidx) do {                                                \
        const char* xb_ = (const char*)x + (unsigned)(cidx) * 16384u;           \
        char* lb_ = (char*)(bufptr) + wv_i * 6144;                              \
        _Pragma("unroll")                                                       \
        for (int k_ = 0; k_ < 6; ++k_)                                          \
            GLL16(xb_ + goff[k_], lb_ + k_ * 1024);                             \
    } while (0)

#define LOADW(arr, cidx) do {                                                   \
        const float* wp_ = Wt + wbase0 + (long)(cidx) * wcstride;               \
        _Pragma("unroll")                                                       \
        for (int q_ = 0; q_ < 18; ++q_) {                                       \
            if (q_ < 9 || full) {                                               \
                vfloat2 v_ = *reinterpret_cast<const vfloat2*>(wp_ + 2 * q_);   \
                arr[2 * q_] = v_.x; arr[2 * q_ + 1] = v_.y;                     \
            } else { arr[2 * q_] = 0.f; arr[2 * q_ + 1] = 0.f; }                \
        }                                                                       \
    } while (0)

#define LOADX_LDS(dst, bi_) do {                                                \
        const char* pb_ = bb_ + (b0 + (bi_)) * 768 + wg * 16;                   \
        _Pragma("unroll")                                                       \
        for (int r_ = 0; r_ < 3; ++r_) {                                        \
            float4 v4_ = *reinterpret_cast<const float4*>(pb_ + r_ * 256);      \
            dst[r_][0] = v4_.x; dst[r_][1] = v4_.y;                             \
            dst[r_][2] = v4_.z; dst[r_][3] = v4_.w;                             \
            if (full) {                                                         \
                vfloat2 v2_ = *reinterpret_cast<const vfloat2*>(pb_ + r_ * 256 + 16); \
                dst[r_][4] = v2_.x; dst[r_][5] = v2_.y;                         \
            } else { dst[r_][4] = 0.f; dst[r_][5] = 0.f; }                      \
        }                                                                       \
    } while (0)

#define FMA36(xc_, warr, bi_)                                                   \
        _Pragma("unroll")                                                       \
        for (int wi_ = 0; wi_ < 4; ++wi_)                                       \
        _Pragma("unroll")                                                       \
        for (int ii_ = 0; ii_ < 3; ++ii_)                                       \
        _Pragma("unroll")                                                       \
        for (int j_ = 0; j_ < 3; ++j_)                                          \
            acc[bi_][wi_] = fmaf(xc_[ii_][wi_ + j_], warr[wi_ * 9 + ii_ * 3 + j_], acc[bi_][wi_]);

#define COMPUTE(bufptr, warr) do {                                              \
        const char* bb_ = (const char*)(bufptr);                                \
        float xA_[3][6], xB_[3][6];                                             \
        LOADX_LDS(xA_, 0);                                                      \
        LOADX_LDS(xB_, 1); FMA36(xA_, warr, 0);                                 \
        LOADX_LDS(xA_, 2); FMA36(xB_, warr, 1);                                 \
        LOADX_LDS(xB_, 3); FMA36(xA_, warr, 2);                                 \
        LOADX_LDS(xA_, 4); FMA36(xB_, warr, 3);                                 \
        LOADX_LDS(xB_, 5); FMA36(xA_, warr, 4);                                 \
        LOADX_LDS(xA_, 6); FMA36(xB_, warr, 5);                                 \
        LOADX_LDS(xB_, 7); FMA36(xA_, warr, 6);                                 \
        FMA36(xB_, warr, 7);                                                    \
    } while (0)

    float wvA[36], wvB[36];

    // ---- prologue: stage c=0, load W(0)
    STAGE(lds[0], 0);
    LOADW(wvA, 0);
    __syncthreads();                 // drains gll(0) + wvA

    // ---- main loop, 2 channels per iteration (static wvA/wvB alternation)
    for (int cc = 0; cc < C_; cc += 2) {
        // phase A: compute c=cc from lds[0]/wvA; prefetch cc+1
        STAGE(lds[1], cc + 1);
        LOADW(wvB, cc + 1);
        COMPUTE(lds[0], wvA);
        __syncthreads();             // drains prefetch; lds[1] ready

        // phase B: compute c=cc+1 from lds[1]/wvB; prefetch cc+2
        if (cc + 2 < C_) {
            STAGE(lds[0], cc + 2);
            LOADW(wvA, cc + 2);
        }
        COMPUTE(lds[1], wvB);
        __syncthreads();
    }

    // ---- epilogue: bias + nontemporal float2 stores (8B-aligned: indices even)
    const float* brow = bias + ((long)o * OH_ + h) * OW_ + w0;
    float2 bv0 = *reinterpret_cast<const float2*>(brow);
    float2 bv1;
    if (full) bv1 = *reinterpret_cast<const float2*>(brow + 2);
    else { bv1.x = 0.f; bv1.y = 0.f; }

#pragma unroll
    for (int bi = 0; bi < 8; ++bi) {
        float* orow = out + (((long)(b0 + bi) * O_ + o) * OH_ + h) * OW_ + w0;
        vfloat2 s0; s0.x = acc[bi][0] + bv0.x; s0.y = acc[bi][1] + bv0.y;
        __builtin_nontemporal_store(s0, reinterpret_cast<vfloat2*>(orow));
        if (full) {
            vfloat2 s1; s1.x = acc[bi][2] + bv1.x; s1.y = acc[bi][3] + bv1.y;
            __builtin_nontemporal_store(s1, reinterpret_cast<vfloat2*>(orow) + 1);
        }
    }

#undef STAGE
#undef LOADW
#undef LOADX_LDS
#undef FMA36
#undef COMPUTE
}

extern "C" void kernel_launch(void* const* d_in, const int* in_sizes, int n_in,
                              void* d_out, int out_size, void* d_ws, size_t ws_size,
                              hipStream_t stream) {
    const float* x    = (const float*)d_in[0];
    const float* Wt   = (const float*)d_in[1];
    const float* bias = (const float*)d_in[2];
    float* out        = (float*)d_out;

    dim3 grid((O_ / 4) * OH_);   // 992 blocks, XCD-swizzled in-kernel
    dim3 block(256);
    lcl_kernel<<<grid, block, 0, stream>>>(x, Wt, bias, out);
}